// Round 9
// baseline (730.183 us; speedup 1.0000x reference)
//
#include <hip/hip_runtime.h>
#include <hip/hip_bf16.h>
#include <cstdint>

typedef unsigned short u16;
typedef __attribute__((ext_vector_type(8))) short short8;
typedef __attribute__((ext_vector_type(4))) float f32x4;

__device__ __forceinline__ u16 f2b(float f) {
  uint32_t u = __float_as_uint(f);
  u += 0x7fffu + ((u >> 16) & 1u);   // RNE to bf16
  return (u16)(u >> 16);
}
__device__ __forceinline__ float b2f(u16 b) {
  return __uint_as_float(((uint32_t)b) << 16);
}
__device__ __forceinline__ uint32_t pk2bf(float a, float b) {
  __hip_bfloat162 t = __float22bfloat162_rn(make_float2(a, b));
  return *(uint32_t*)&t;   // packed {lo=a, hi=b}
}

// Manual grid barrier. r8 lesson: polling with atomicAdd(c,0) (an RMW) from
// 1536 blocks collapses the L2 atomic unit (~300us/barrier — arrivals starve
// behind polls). Poll with an atomic LOAD (parallel/broadcast at L2, no
// serialization); arrive with one RMW per block. s_sleep(16) ~0.4us cuts poll
// pressure. Co-residency guaranteed by exact-capacity grids -> no deadlock.
__device__ __forceinline__ void gsync(unsigned* c, unsigned target) {
  __threadfence();                 // release
  __syncthreads();
  if (threadIdx.x == 0) {
    __hip_atomic_fetch_add(c, 1u, __ATOMIC_ACQ_REL, __HIP_MEMORY_SCOPE_AGENT);
    while (__hip_atomic_load(c, __ATOMIC_ACQUIRE, __HIP_MEMORY_SCOPE_AGENT) < target) {
      __builtin_amdgcn_s_sleep(16);
    }
  }
  __syncthreads();
  __threadfence();                 // acquire
}

// ---------------------------------------------------------------------------
// K1: cast (grid-stride) + gsync + merged projection GEMMs.
// 1536 blocks x 256 thr = exactly 6 blk/CU (VGPR 40, LDS 18.4KB) -> resident.
// ---------------------------------------------------------------------------
__global__ __launch_bounds__(256, 6) void k_proj(
    const float* __restrict__ Q, const float* __restrict__ K,
    const float* __restrict__ Wq, const float* __restrict__ Wk,
    const float* __restrict__ Wv, const float* __restrict__ Wo,
    const float* __restrict__ bq, const float* __restrict__ bk,
    const float* __restrict__ bv,
    u16* __restrict__ xq, u16* __restrict__ xk,
    u16* __restrict__ wqb, u16* __restrict__ wkb,
    u16* __restrict__ wvb, u16* __restrict__ wob,
    u16* __restrict__ qb, u16* __restrict__ kb, u16* __restrict__ vT,
    unsigned* __restrict__ cnt) {
  __shared__ __align__(16) u16 sA[64 * 72];
  __shared__ __align__(16) u16 sB[64 * 72];

  // ---- phase 1: cast fp32 -> bf16 (grid-stride over 2,097,152 float4) ----
  for (int g = blockIdx.x * 256 + threadIdx.x; g < 2097152; g += 393216) {
    const float* src; u16* dst; int off;
    if      (g <  524288) { src = Q;  dst = xq;  off = g; }
    else if (g < 1048576) { src = K;  dst = xk;  off = g -  524288; }
    else if (g < 1310720) { src = Wq; dst = wqb; off = g - 1048576; }
    else if (g < 1572864) { src = Wk; dst = wkb; off = g - 1310720; }
    else if (g < 1835008) { src = Wv; dst = wvb; off = g - 1572864; }
    else                  { src = Wo; dst = wob; off = g - 1835008; }
    float4 v = reinterpret_cast<const float4*>(src)[off];
    ushort4 o4;
    o4.x = f2b(v.x); o4.y = f2b(v.y); o4.z = f2b(v.z); o4.w = f2b(v.w);
    reinterpret_cast<ushort4*>(dst)[off] = o4;
  }

  gsync(cnt, 1536u);

  // ---- phase 2: gemm3 (r2-proven body; z from blockIdx) ----
  const int t = threadIdx.x, b = blockIdx.x;
  const int z = b >> 9, blk = b & 511;
  const int xcd = blk & 7, lid = blk >> 3;   // 64 blocks per XCD slice
  const u16 *A, *B; const float* bias; u16* C; int ldC, mbase, nbase; bool brow;
  if (z == 0)      { A = xq; B = wqb; bias = bq; C = qb; ldC = 1024;
                     mbase = (xcd * 4 + (lid >> 4)) * 64; nbase = (lid & 15) * 64; brow = false; }
  else if (z == 1) { A = xk; B = wkb; bias = bk; C = kb; ldC = 1024;
                     mbase = (xcd * 4 + (lid >> 4)) * 64; nbase = (lid & 15) * 64; brow = false; }
  else             { A = wvb; B = xk; bias = bv; C = vT; ldC = 2048;
                     mbase = (xcd * 2 + (lid >> 5)) * 64; nbase = (lid & 31) * 64; brow = true; }
  const int lane = t & 63, wid = t >> 6;
  const int wy = wid >> 1, wx = wid & 1;
  const int m = lane & 15, quad = lane >> 4;
  const int srow = t >> 2, scb = (t & 3) * 16;
  const u16* gA = A + (mbase + srow) * 1024 + scb;
  const u16* gB = B + (nbase + srow) * 1024 + scb;
  uint4 ra0 = *(const uint4*)(gA), ra1 = *(const uint4*)(gA + 8);
  uint4 rb0 = *(const uint4*)(gB), rb1 = *(const uint4*)(gB + 8);

  f32x4 acc[2][2];
#pragma unroll
  for (int i = 0; i < 2; i++)
#pragma unroll
    for (int j = 0; j < 2; j++) acc[i][j] = (f32x4){0.f, 0.f, 0.f, 0.f};

  for (int kb_ = 0; kb_ < 16; ++kb_) {
    __syncthreads();
    *(uint4*)(&sA[srow * 72 + scb])     = ra0;
    *(uint4*)(&sA[srow * 72 + scb + 8]) = ra1;
    *(uint4*)(&sB[srow * 72 + scb])     = rb0;
    *(uint4*)(&sB[srow * 72 + scb + 8]) = rb1;
    if (kb_ < 15) {
      ra0 = *(const uint4*)(gA + (kb_ + 1) * 64);
      ra1 = *(const uint4*)(gA + (kb_ + 1) * 64 + 8);
      rb0 = *(const uint4*)(gB + (kb_ + 1) * 64);
      rb1 = *(const uint4*)(gB + (kb_ + 1) * 64 + 8);
    }
    __syncthreads();
    short8 af[2][2], bf[2][2];
#pragma unroll
    for (int mi = 0; mi < 2; mi++)
#pragma unroll
      for (int ks = 0; ks < 2; ks++)
        af[mi][ks] = *(const short8*)(
            &sA[(wy * 32 + mi * 16 + m) * 72 + ks * 32 + quad * 8]);
#pragma unroll
    for (int ni = 0; ni < 2; ni++)
#pragma unroll
      for (int ks = 0; ks < 2; ks++)
        bf[ni][ks] = *(const short8*)(
            &sB[(wx * 32 + ni * 16 + m) * 72 + ks * 32 + quad * 8]);
#pragma unroll
    for (int ks = 0; ks < 2; ks++)
#pragma unroll
      for (int mi = 0; mi < 2; mi++)
#pragma unroll
        for (int ni = 0; ni < 2; ni++)
          acc[mi][ni] = __builtin_amdgcn_mfma_f32_16x16x32_bf16(
              af[mi][ks], bf[ni][ks], acc[mi][ni], 0, 0, 0);
  }

#pragma unroll
  for (int mi = 0; mi < 2; mi++)
#pragma unroll
    for (int ni = 0; ni < 2; ni++) {
      const int col = nbase + wx * 32 + ni * 16 + m;
      const float bcol = brow ? 0.f : bias[col];
#pragma unroll
      for (int r = 0; r < 4; r++) {
        const int row = mbase + wy * 32 + mi * 16 + quad * 4 + r;
        const float bval = brow ? bias[row] : bcol;
        C[row * ldC + col] = f2b(acc[mi][ni][r] + bval);
      }
    }
}

// ---------------------------------------------------------------------------
// K2: flash + gsync + combine + gsync + gemm_out. 512 blocks x 256 thr =
// exactly the LDS-limited co-residency (55.3KB -> 2 blk/CU); barrier safe.
// ---------------------------------------------------------------------------
__global__ __launch_bounds__(256, 2) void k_attn(
    const u16* __restrict__ qb, const u16* __restrict__ kb,
    const u16* __restrict__ vT, const u16* __restrict__ wob,
    const float* __restrict__ bo, u16* __restrict__ po,
    float* __restrict__ lp, u16* __restrict__ ob,
    float* __restrict__ out, unsigned* __restrict__ cnt) {
  __shared__ __align__(16) u16 smem[27648];   // 55296 B
  const int t = threadIdx.x, b = blockIdx.x;
  const int lane = t & 63, wid = t >> 6;
  const int m = lane & 15, quad = lane >> 4;

  // ======================= phase 1: flash =======================
  {
    u16* sK = smem;            // 64*72
    u16* sV = smem + 4608;     // 64*72  [dim][key]
    u16* sP = smem + 9216;     // 4*64*72 per-wave [q(64)][key]
    const int qt = b & 7, h = (b >> 3) & 15, sp = b >> 7;
    const int colbase = h * 64;
    const int pbase = wid * 4608;  // 64*72 per wave
    const int kbase = sp * 512;    // 4 splits x 512 keys
    const int qwave = qt * 256 + wid * 64;

    short8 aq[4][2];   // B-operand: lane holds Q[q=mi*16+m][d=g*32+quad*8+j]
#pragma unroll
    for (int mi = 0; mi < 4; mi++)
#pragma unroll
      for (int g = 0; g < 2; g++)
        aq[mi][g] = *(const short8*)(
            &qb[(qwave + mi * 16 + m) * 1024 + colbase + g * 32 + quad * 8]);

    f32x4 o[4][4];
    float lpart[4] = {0.f, 0.f, 0.f, 0.f};
#pragma unroll
    for (int mi = 0; mi < 4; mi++)
#pragma unroll
      for (int nt = 0; nt < 4; nt++) o[mi][nt] = (f32x4){0.f, 0.f, 0.f, 0.f};

    const int srow = t >> 2, scb = (t & 3) * 16;
    const u16* gK = kb + (kbase + srow) * 1024 + colbase + scb;
    const u16* gV = vT + (colbase + srow) * 2048 + kbase + scb;

    uint4 rk0 = *(const uint4*)(gK), rk1 = *(const uint4*)(gK + 8);
    uint4 rv0 = *(const uint4*)(gV), rv1 = *(const uint4*)(gV + 8);

    uint32_t* sP32 = (uint32_t*)sP;

    for (int kt = 0; kt < 8; ++kt) {
      __syncthreads();
      *(uint4*)(&sK[srow * 72 + scb])     = rk0;
      *(uint4*)(&sK[srow * 72 + scb + 8]) = rk1;
      *(uint4*)(&sV[srow * 72 + scb])     = rv0;
      *(uint4*)(&sV[srow * 72 + scb + 8]) = rv1;
      if (kt < 7) {
        rk0 = *(const uint4*)(gK + (kt + 1) * 65536);
        rk1 = *(const uint4*)(gK + (kt + 1) * 65536 + 8);
        rv0 = *(const uint4*)(gV + (kt + 1) * 64);
        rv1 = *(const uint4*)(gV + (kt + 1) * 64 + 8);
      }
      __syncthreads();

      // S^T tiles: D[key=nt*16+quad*4+r][q=mi*16+m], raw logits
#pragma unroll
      for (int nt = 0; nt < 4; nt++) {
        short8 bk0 = *(const short8*)(&sK[(nt * 16 + m) * 72 + quad * 8]);
        short8 bk1 = *(const short8*)(&sK[(nt * 16 + m) * 72 + 32 + quad * 8]);
#pragma unroll
        for (int mi = 0; mi < 4; mi++) {
          f32x4 st = (f32x4){0.f, 0.f, 0.f, 0.f};
          st = __builtin_amdgcn_mfma_f32_16x16x32_bf16(bk0, aq[mi][0], st, 0, 0, 0);
          st = __builtin_amdgcn_mfma_f32_16x16x32_bf16(bk1, aq[mi][1], st, 0, 0, 0);
          // p = exp(s - 16) (fixed shift; no running max needed)
          float p0 = __expf(st[0] - 16.0f);
          float p1 = __expf(st[1] - 16.0f);
          float p2 = __expf(st[2] - 16.0f);
          float p3 = __expf(st[3] - 16.0f);
          lpart[mi] += (p0 + p1) + (p2 + p3);
          const int pa_ = pbase + (mi * 16 + m) * 72 + nt * 16 + quad * 4;
          sP32[pa_ >> 1]       = pk2bf(p0, p1);
          sP32[(pa_ >> 1) + 1] = pk2bf(p2, p3);
        }
      }

      // O += P V  (A-operand read of sP: lane holds P[q=mi*16+m][key=g*32+quad*8+j])
      short8 pa[4][2];
#pragma unroll
      for (int mi = 0; mi < 4; mi++)
#pragma unroll
        for (int g = 0; g < 2; g++)
          pa[mi][g] = *(const short8*)(&sP[pbase + (mi * 16 + m) * 72 + g * 32 + quad * 8]);
#pragma unroll
      for (int nt = 0; nt < 4; nt++) {
        short8 bv0 = *(const short8*)(&sV[(nt * 16 + m) * 72 + quad * 8]);
        short8 bv1 = *(const short8*)(&sV[(nt * 16 + m) * 72 + 32 + quad * 8]);
#pragma unroll
        for (int mi = 0; mi < 4; mi++) {
          o[mi][nt] = __builtin_amdgcn_mfma_f32_16x16x32_bf16(pa[mi][0], bv0, o[mi][nt], 0, 0, 0);
          o[mi][nt] = __builtin_amdgcn_mfma_f32_16x16x32_bf16(pa[mi][1], bv1, o[mi][nt], 0, 0, 0);
        }
      }
    }

    // l: per-lane partial covers keys {nt*16+quad*4+r}; reduce over quads.
#pragma unroll
    for (int mi = 0; mi < 4; mi++) {
      float l = lpart[mi];
      l += __shfl_xor(l, 16);
      l += __shfl_xor(l, 32);
      if (quad == 0)
        lp[(sp * 16 + h) * 2048 + qwave + mi * 16 + m] = l;
    }

    // Coalesced po epilogue via in-LDS transpose (wave-private region).
    u16* sO = &sP[pbase];
#pragma unroll
    for (int mi = 0; mi < 4; mi++)
#pragma unroll
      for (int nt = 0; nt < 4; nt++)
#pragma unroll
        for (int r = 0; r < 4; r++)
          sO[(mi * 16 + quad * 4 + r) * 72 + nt * 16 + m] = f2b(o[mi][nt][r]);

    const int rrow = lane >> 3, rcol = (lane & 7) * 8;
    const int gbase = ((sp * 16 + h) * 2048 + qwave) * 64;
#pragma unroll
    for (int g = 0; g < 8; g++) {
      const int row = g * 8 + rrow;
      short8 v = *(const short8*)&sO[row * 72 + rcol];
      *(short8*)&po[gbase + row * 64 + rcol] = v;
    }
  }

  gsync(cnt, 512u);

  // ======================= phase 2: combine (x4 grid-stride) ==============
  {
#pragma unroll
    for (int i = 0; i < 4; i++) {
      const int idx = i * 131072 + b * 256 + t;    // 524288 total
      const int dq = idx & 15, qg = (idx >> 4) & 2047, h = idx >> 15;
      float acc0 = 0.f, acc1 = 0.f, acc2 = 0.f, acc3 = 0.f, l = 0.f;
#pragma unroll
      for (int s = 0; s < 4; s++) {
        const ushort4 p4 = *(const ushort4*)&po[(((s * 16 + h) * 2048 + qg) * 64) + dq * 4];
        acc0 += b2f(p4.x); acc1 += b2f(p4.y); acc2 += b2f(p4.z); acc3 += b2f(p4.w);
        l += lp[(s * 16 + h) * 2048 + qg];
      }
      const float inv = 1.0f / (l * 32.0f);
      const ushort4 q4 = *(const ushort4*)&qb[qg * 1024 + h * 64 + dq * 4];
      ushort4 o4;
      o4.x = f2b(b2f(q4.x) + acc0 * inv);
      o4.y = f2b(b2f(q4.y) + acc1 * inv);
      o4.z = f2b(b2f(q4.z) + acc2 * inv);
      o4.w = f2b(b2f(q4.w) + acc3 * inv);
      *(ushort4*)&ob[(h * 128 + (qg >> 4)) * 1024 + (qg & 15) * 64 + dq * 4] = o4;
    }
  }

  gsync(cnt, 1024u);

  // ======================= phase 3: gemm_out =======================
  {
    u16* sA = smem;            // 64*72
    u16* sB = smem + 4608;     // 64*72
    const int xcd = b & 7, lid = b >> 3;   // 64 blocks per XCD slice
    const int mbase = (xcd * 4 + (lid >> 4)) * 64, nbase = (lid & 15) * 64;
    const int wy = wid >> 1, wx = wid & 1;
    const int srow = t >> 2, scb = (t & 3) * 16;
    const u16* gA = ob + (mbase + srow) * 1024 + scb;
    const u16* gB = wob + (nbase + srow) * 1024 + scb;
    uint4 ra0 = *(const uint4*)(gA), ra1 = *(const uint4*)(gA + 8);
    uint4 rb0 = *(const uint4*)(gB), rb1 = *(const uint4*)(gB + 8);

    f32x4 acc[2][2];
#pragma unroll
    for (int i = 0; i < 2; i++)
#pragma unroll
      for (int j = 0; j < 2; j++) acc[i][j] = (f32x4){0.f, 0.f, 0.f, 0.f};

    for (int kb_ = 0; kb_ < 16; ++kb_) {
      __syncthreads();
      *(uint4*)(&sA[srow * 72 + scb])     = ra0;
      *(uint4*)(&sA[srow * 72 + scb + 8]) = ra1;
      *(uint4*)(&sB[srow * 72 + scb])     = rb0;
      *(uint4*)(&sB[srow * 72 + scb + 8]) = rb1;
      if (kb_ < 15) {
        ra0 = *(const uint4*)(gA + (kb_ + 1) * 64);
        ra1 = *(const uint4*)(gA + (kb_ + 1) * 64 + 8);
        rb0 = *(const uint4*)(gB + (kb_ + 1) * 64);
        rb1 = *(const uint4*)(gB + (kb_ + 1) * 64 + 8);
      }
      __syncthreads();
      short8 af[2][2], bf[2][2];
#pragma unroll
      for (int mi = 0; mi < 2; mi++)
#pragma unroll
        for (int ks = 0; ks < 2; ks++)
          af[mi][ks] = *(const short8*)(
              &sA[(wy * 32 + mi * 16 + m) * 72 + ks * 32 + quad * 8]);
#pragma unroll
      for (int ni = 0; ni < 2; ni++)
#pragma unroll
        for (int ks = 0; ks < 2; ks++)
          bf[ni][ks] = *(const short8*)(
              &sB[(wx * 32 + ni * 16 + m) * 72 + ks * 32 + quad * 8]);
#pragma unroll
      for (int ks = 0; ks < 2; ks++)
#pragma unroll
        for (int mi = 0; mi < 2; mi++)
#pragma unroll
          for (int ni = 0; ni < 2; ni++)
            acc[mi][ni] = __builtin_amdgcn_mfma_f32_16x16x32_bf16(
                af[mi][ks], bf[ni][ks], acc[mi][ni], 0, 0, 0);
    }

#pragma unroll
    for (int mi = 0; mi < 2; mi++)
#pragma unroll
      for (int ni = 0; ni < 2; ni++) {
        const int col = nbase + wx * 32 + ni * 16 + m;
        const float bcol = bo[col];
#pragma unroll
        for (int r = 0; r < 4; r++) {
          const int row = mbase + wy * 32 + mi * 16 + quad * 4 + r;
          out[row * 1024 + col] =
              b2f(ob[row * 1024 + col]) + fmaxf(acc[mi][ni][r] + bcol, 0.f);
        }
      }
  }
}

// ---------------------------------------------------------------------------
extern "C" void kernel_launch(void* const* d_in, const int* in_sizes, int n_in,
                              void* d_out, int out_size, void* d_ws, size_t ws_size,
                              hipStream_t stream) {
  const float* Q  = (const float*)d_in[0];
  const float* K  = (const float*)d_in[1];
  const float* Wq = (const float*)d_in[2];
  const float* bq = (const float*)d_in[3];
  const float* Wk = (const float*)d_in[4];
  const float* bk = (const float*)d_in[5];
  const float* Wv = (const float*)d_in[6];
  const float* bv = (const float*)d_in[7];
  const float* Wo = (const float*)d_in[8];
  const float* bo = (const float*)d_in[9];
  float* out = (float*)d_out;

  u16* ws = (u16*)d_ws;            // 256 MB ws; flat layout
  u16* xq  = ws;                   // 2M u16
  u16* xk  = xq  + 2097152;        // 2M
  u16* wqb = xk  + 2097152;        // 1M
  u16* wkb = wqb + 1048576;        // 1M
  u16* wvb = wkb + 1048576;        // 1M
  u16* wob = wvb + 1048576;        // 1M
  u16* qb  = wob + 1048576;        // 2M
  u16* kb  = qb  + 2097152;        // 2M
  u16* vT  = kb  + 2097152;        // 2M  (v projected TRANSPOSED [1024][2048])
  u16* ob  = vT  + 2097152;        // 2M  (attention out, scrambled)
  u16* po  = ob  + 2097152;        // 8M  (4 splits x 16 h x 2048 q x 64 d)
  float* lp = (float*)(po + 8388608);  // 4x16x2048 fp32
  unsigned* cnt = (unsigned*)(lp + 131072);  // 2 barrier counters

  hipMemsetAsync(cnt, 0, 8, stream);

  k_proj<<<1536, 256, 0, stream>>>(Q, K, Wq, Wk, Wv, Wo, bq, bk, bv,
                                   xq, xk, wqb, wkb, wvb, wob, qb, kb, vT,
                                   cnt);

  k_attn<<<512, 256, 0, stream>>>(qb, kb, vT, wob, bo, po, lp, ob, out,
                                  cnt + 1);
}

// Round 10
// 258.423 us; speedup vs baseline: 2.8255x; 2.8255x over previous
//
#include <hip/hip_runtime.h>
#include <hip/hip_bf16.h>
#include <cstdint>

typedef unsigned short u16;
typedef __attribute__((ext_vector_type(8))) short short8;
typedef __attribute__((ext_vector_type(4))) float f32x4;

__device__ __forceinline__ u16 f2b(float f) {
  uint32_t u = __float_as_uint(f);
  u += 0x7fffu + ((u >> 16) & 1u);   // RNE to bf16
  return (u16)(u >> 16);
}
__device__ __forceinline__ float b2f(u16 b) {
  return __uint_as_float(((uint32_t)b) << 16);
}
__device__ __forceinline__ uint32_t pk2bf(float a, float b) {
  __hip_bfloat162 t = __float22bfloat162_rn(make_float2(a, b));
  return *(uint32_t*)&t;   // packed {lo=a, hi=b}
}
// pack 8 fp32 (two float4) -> uint4 of 8 bf16 (RNE, identical to cast_all)
__device__ __forceinline__ uint4 pk8(const float4 a, const float4 b) {
  uint4 r;
  r.x = pk2bf(a.x, a.y); r.y = pk2bf(a.z, a.w);
  r.z = pk2bf(b.x, b.y); r.w = pk2bf(b.z, b.w);
  return r;
}

// ---------------------------------------------------------------------------
// Merged projection GEMMs, 64x64 tile (r2-proven geometry), fp32 inputs with
// cast fused into LDS staging (cast_all kernel eliminated). At this tile the
// fp32 prefetch is only 8 float4 = 32 VGPRs (r1's failure was 48 at 128x64).
// z=0: qb = Q*Wq^T + bq          (M=2048,N=1024)
// z=1: kb = K*Wk^T + bk          (M=2048,N=1024)
// z=2: vT = Wv*K^T + bv[row]     (M=1024,N=2048)  <- V produced TRANSPOSED
// ---------------------------------------------------------------------------
__global__ __launch_bounds__(256) void gemm3(
    const float* __restrict__ Q, const float* __restrict__ K,
    const float* __restrict__ Wq, const float* __restrict__ Wk,
    const float* __restrict__ Wv,
    const float* __restrict__ bq, const float* __restrict__ bk,
    const float* __restrict__ bv,
    u16* __restrict__ qb, u16* __restrict__ kb, u16* __restrict__ vT) {
  __shared__ __align__(16) u16 sA[64 * 72];
  __shared__ __align__(16) u16 sB[64 * 72];
  const int t = threadIdx.x, blk = blockIdx.x, z = blockIdx.y;
  const int xcd = blk & 7, lid = blk >> 3;   // 64 blocks per XCD slice
  const float *A, *B; const float* bias; u16* C; int ldC, mbase, nbase; bool brow;
  if (z == 0)      { A = Q;  B = Wq; bias = bq; C = qb; ldC = 1024;
                     mbase = (xcd * 4 + (lid >> 4)) * 64; nbase = (lid & 15) * 64; brow = false; }
  else if (z == 1) { A = K;  B = Wk; bias = bk; C = kb; ldC = 1024;
                     mbase = (xcd * 4 + (lid >> 4)) * 64; nbase = (lid & 15) * 64; brow = false; }
  else             { A = Wv; B = K;  bias = bv; C = vT; ldC = 2048;
                     mbase = (xcd * 2 + (lid >> 5)) * 64; nbase = (lid & 31) * 64; brow = true; }
  const int lane = t & 63, wid = t >> 6;
  const int wy = wid >> 1, wx = wid & 1;
  const int m = lane & 15, quad = lane >> 4;
  const int srow = t >> 2, scb = (t & 3) * 16;
  const float* gA = A + (mbase + srow) * 1024 + scb;
  const float* gB = B + (nbase + srow) * 1024 + scb;
  float4 ra0 = *(const float4*)(gA),     ra1 = *(const float4*)(gA + 4);
  float4 ra2 = *(const float4*)(gA + 8), ra3 = *(const float4*)(gA + 12);
  float4 rb0 = *(const float4*)(gB),     rb1 = *(const float4*)(gB + 4);
  float4 rb2 = *(const float4*)(gB + 8), rb3 = *(const float4*)(gB + 12);

  f32x4 acc[2][2];
#pragma unroll
  for (int i = 0; i < 2; i++)
#pragma unroll
    for (int j = 0; j < 2; j++) acc[i][j] = (f32x4){0.f, 0.f, 0.f, 0.f};

  for (int kb_ = 0; kb_ < 16; ++kb_) {
    __syncthreads();
    *(uint4*)(&sA[srow * 72 + scb])     = pk8(ra0, ra1);
    *(uint4*)(&sA[srow * 72 + scb + 8]) = pk8(ra2, ra3);
    *(uint4*)(&sB[srow * 72 + scb])     = pk8(rb0, rb1);
    *(uint4*)(&sB[srow * 72 + scb + 8]) = pk8(rb2, rb3);
    if (kb_ < 15) {
      const float* pA = gA + (kb_ + 1) * 64;
      ra0 = *(const float4*)(pA);     ra1 = *(const float4*)(pA + 4);
      ra2 = *(const float4*)(pA + 8); ra3 = *(const float4*)(pA + 12);
      const float* pB = gB + (kb_ + 1) * 64;
      rb0 = *(const float4*)(pB);     rb1 = *(const float4*)(pB + 4);
      rb2 = *(const float4*)(pB + 8); rb3 = *(const float4*)(pB + 12);
    }
    __syncthreads();
    short8 af[2][2], bf[2][2];
#pragma unroll
    for (int mi = 0; mi < 2; mi++)
#pragma unroll
      for (int ks = 0; ks < 2; ks++)
        af[mi][ks] = *(const short8*)(
            &sA[(wy * 32 + mi * 16 + m) * 72 + ks * 32 + quad * 8]);
#pragma unroll
    for (int ni = 0; ni < 2; ni++)
#pragma unroll
      for (int ks = 0; ks < 2; ks++)
        bf[ni][ks] = *(const short8*)(
            &sB[(wx * 32 + ni * 16 + m) * 72 + ks * 32 + quad * 8]);
#pragma unroll
    for (int ks = 0; ks < 2; ks++)
#pragma unroll
      for (int mi = 0; mi < 2; mi++)
#pragma unroll
        for (int ni = 0; ni < 2; ni++)
          acc[mi][ni] = __builtin_amdgcn_mfma_f32_16x16x32_bf16(
              af[mi][ks], bf[ni][ks], acc[mi][ni], 0, 0, 0);
  }

#pragma unroll
  for (int mi = 0; mi < 2; mi++)
#pragma unroll
    for (int ni = 0; ni < 2; ni++) {
      const int col = nbase + wx * 32 + ni * 16 + m;
      const float bcol = brow ? 0.f : bias[col];
#pragma unroll
      for (int r = 0; r < 4; r++) {
        const int row = mbase + wy * 32 + mi * 16 + quad * 4 + r;
        const float bval = brow ? bias[row] : bcol;
        C[row * ldC + col] = f2b(acc[mi][ni][r] + bval);
      }
    }
}

// ---------------------------------------------------------------------------
// Flash attention (r6-proven body) + fused split-K combine: after po/lp
// stores, each block arrives at its (h,qt) group counter (4 blocks/group,
// 128 groups — negligible atomic contention, no spinning, no co-residency
// requirement). The last-arriving block acquires and combines its 256-q
// chunk. Standard CUDA threadFenceReduction pattern.
// ---------------------------------------------------------------------------
__global__ __launch_bounds__(256, 2) void flash(
    const u16* __restrict__ q, const u16* __restrict__ k,
    const u16* __restrict__ vT, u16* __restrict__ po, float* __restrict__ lp,
    u16* __restrict__ ob, unsigned* __restrict__ cnt) {
  __shared__ __align__(16) u16 sK[64 * 72];
  __shared__ __align__(16) u16 sV[64 * 72];     // [dim][key]
  __shared__ __align__(16) u16 sP[4 * 64 * 72]; // per-wave [q(64)][key]
  __shared__ unsigned s_old;
  const int t = threadIdx.x;
  const int qt = blockIdx.x, h = blockIdx.y, sp = blockIdx.z;
  const int lane = t & 63, wid = t >> 6;
  const int m = lane & 15, quad = lane >> 4;
  const int colbase = h * 64;
  const int pbase = wid * 4608;  // 64*72 per wave
  const int kbase = sp * 512;    // 4 splits x 512 keys
  const int qwave = qt * 256 + wid * 64;

  short8 aq[4][2];   // B-operand: lane holds Q[q=mi*16+m][d=g*32+quad*8+j]
#pragma unroll
  for (int mi = 0; mi < 4; mi++)
#pragma unroll
    for (int g = 0; g < 2; g++)
      aq[mi][g] = *(const short8*)(
          &q[(qwave + mi * 16 + m) * 1024 + colbase + g * 32 + quad * 8]);

  f32x4 o[4][4];
  float lpart[4] = {0.f, 0.f, 0.f, 0.f};
#pragma unroll
  for (int mi = 0; mi < 4; mi++)
#pragma unroll
    for (int nt = 0; nt < 4; nt++) o[mi][nt] = (f32x4){0.f, 0.f, 0.f, 0.f};

  const int srow = t >> 2, scb = (t & 3) * 16;
  const u16* gK = k + (kbase + srow) * 1024 + colbase + scb;
  const u16* gV = vT + (colbase + srow) * 2048 + kbase + scb;

  uint4 rk0 = *(const uint4*)(gK), rk1 = *(const uint4*)(gK + 8);
  uint4 rv0 = *(const uint4*)(gV), rv1 = *(const uint4*)(gV + 8);

  uint32_t* sP32 = (uint32_t*)sP;

  for (int kt = 0; kt < 8; ++kt) {
    __syncthreads();
    *(uint4*)(&sK[srow * 72 + scb])     = rk0;
    *(uint4*)(&sK[srow * 72 + scb + 8]) = rk1;
    *(uint4*)(&sV[srow * 72 + scb])     = rv0;
    *(uint4*)(&sV[srow * 72 + scb + 8]) = rv1;
    if (kt < 7) {
      rk0 = *(const uint4*)(gK + (kt + 1) * 65536);
      rk1 = *(const uint4*)(gK + (kt + 1) * 65536 + 8);
      rv0 = *(const uint4*)(gV + (kt + 1) * 64);
      rv1 = *(const uint4*)(gV + (kt + 1) * 64 + 8);
    }
    __syncthreads();

    // S^T tiles: D[key=nt*16+quad*4+r][q=mi*16+m], raw logits
#pragma unroll
    for (int nt = 0; nt < 4; nt++) {
      short8 bk0 = *(const short8*)(&sK[(nt * 16 + m) * 72 + quad * 8]);
      short8 bk1 = *(const short8*)(&sK[(nt * 16 + m) * 72 + 32 + quad * 8]);
#pragma unroll
      for (int mi = 0; mi < 4; mi++) {
        f32x4 st = (f32x4){0.f, 0.f, 0.f, 0.f};
        st = __builtin_amdgcn_mfma_f32_16x16x32_bf16(bk0, aq[mi][0], st, 0, 0, 0);
        st = __builtin_amdgcn_mfma_f32_16x16x32_bf16(bk1, aq[mi][1], st, 0, 0, 0);
        // p = exp(s - 16) (fixed shift; no running max needed)
        float p0 = __expf(st[0] - 16.0f);
        float p1 = __expf(st[1] - 16.0f);
        float p2 = __expf(st[2] - 16.0f);
        float p3 = __expf(st[3] - 16.0f);
        lpart[mi] += (p0 + p1) + (p2 + p3);
        const int pa_ = pbase + (mi * 16 + m) * 72 + nt * 16 + quad * 4;
        sP32[pa_ >> 1]       = pk2bf(p0, p1);
        sP32[(pa_ >> 1) + 1] = pk2bf(p2, p3);
      }
    }

    // O += P V  (A-operand read of sP: lane holds P[q=mi*16+m][key=g*32+quad*8+j])
    short8 pa[4][2];
#pragma unroll
    for (int mi = 0; mi < 4; mi++)
#pragma unroll
      for (int g = 0; g < 2; g++)
        pa[mi][g] = *(const short8*)(&sP[pbase + (mi * 16 + m) * 72 + g * 32 + quad * 8]);
#pragma unroll
    for (int nt = 0; nt < 4; nt++) {
      short8 bv0 = *(const short8*)(&sV[(nt * 16 + m) * 72 + quad * 8]);
      short8 bv1 = *(const short8*)(&sV[(nt * 16 + m) * 72 + 32 + quad * 8]);
#pragma unroll
      for (int mi = 0; mi < 4; mi++) {
        o[mi][nt] = __builtin_amdgcn_mfma_f32_16x16x32_bf16(pa[mi][0], bv0, o[mi][nt], 0, 0, 0);
        o[mi][nt] = __builtin_amdgcn_mfma_f32_16x16x32_bf16(pa[mi][1], bv1, o[mi][nt], 0, 0, 0);
      }
    }
  }

  // l: per-lane partial covers keys {nt*16+quad*4+r}; reduce over quads.
#pragma unroll
  for (int mi = 0; mi < 4; mi++) {
    float l = lpart[mi];
    l += __shfl_xor(l, 16);
    l += __shfl_xor(l, 32);
    if (quad == 0)
      lp[(sp * 16 + h) * 2048 + qwave + mi * 16 + m] = l;
  }

  // Coalesced po epilogue via in-LDS transpose (wave-private region).
  u16* sO = &sP[pbase];
#pragma unroll
  for (int mi = 0; mi < 4; mi++)
#pragma unroll
    for (int nt = 0; nt < 4; nt++)
#pragma unroll
      for (int r = 0; r < 4; r++)
        sO[(mi * 16 + quad * 4 + r) * 72 + nt * 16 + m] = f2b(o[mi][nt][r]);

  const int rrow = lane >> 3, rcol = (lane & 7) * 8;
  const int gbase = ((sp * 16 + h) * 2048 + qwave) * 64;
#pragma unroll
  for (int g = 0; g < 8; g++) {
    const int row = g * 8 + rrow;
    short8 v = *(const short8*)&sO[row * 72 + rcol];
    *(short8*)&po[gbase + row * 64 + rcol] = v;
  }

  // ---- fused split-K combine: last block of the 4-(sp) group does it ----
  __threadfence();                 // release this block's po/lp (all threads)
  __syncthreads();                 // all fences precede the arrive
  if (t == 0) s_old = atomicAdd(&cnt[h * 8 + qt], 1u);
  __syncthreads();
  if (s_old == 3u) {
    __threadfence();               // acquire other blocks' po/lp
#pragma unroll
    for (int i = 0; i < 16; ++i) {
      const int il = i * 256 + t;            // 4096 ushort4 units
      const int dq = il & 15, qgl = il >> 4;  // qgl 0..255
      const int qg = qt * 256 + qgl;
      float acc0 = 0.f, acc1 = 0.f, acc2 = 0.f, acc3 = 0.f, l = 0.f;
#pragma unroll
      for (int s = 0; s < 4; s++) {
        const ushort4 p4 = *(const ushort4*)&po[(((s * 16 + h) * 2048 + qg) * 64) + dq * 4];
        acc0 += b2f(p4.x); acc1 += b2f(p4.y); acc2 += b2f(p4.z); acc3 += b2f(p4.w);
        l += lp[(s * 16 + h) * 2048 + qg];
      }
      const float inv = 1.0f / (l * 32.0f);
      const ushort4 q4 = *(const ushort4*)&q[qg * 1024 + h * 64 + dq * 4];
      ushort4 o4;
      o4.x = f2b(b2f(q4.x) + acc0 * inv);
      o4.y = f2b(b2f(q4.y) + acc1 * inv);
      o4.z = f2b(b2f(q4.z) + acc2 * inv);
      o4.w = f2b(b2f(q4.w) + acc3 * inv);
      *(ushort4*)&ob[(h * 128 + (qg >> 4)) * 1024 + (qg & 15) * 64 + dq * 4] = o4;
    }
  }
}

// ---------------------------------------------------------------------------
// Final GEMM: out = Res + relu(A*B^T + bias), M=2048 N=1024, fp32 out.
// A (ob) bf16; B (Wo) fp32 with cast fused into staging (+8 VGPRs only).
// 64x64 tile, BK=64, 512 blocks (2/CU).
// ---------------------------------------------------------------------------
__global__ __launch_bounds__(256) void gemm_out(
    const u16* __restrict__ A, const float* __restrict__ B,
    const float* __restrict__ bias, const u16* __restrict__ Res,
    float* __restrict__ out) {
  __shared__ __align__(16) u16 sA[64 * 72];
  __shared__ __align__(16) u16 sB[64 * 72];
  const int t = threadIdx.x, blk = blockIdx.x;
  const int xcd = blk & 7, lid = blk >> 3;   // 64 blocks per XCD slice
  const int mbase = (xcd * 4 + (lid >> 4)) * 64, nbase = (lid & 15) * 64;
  const int lane = t & 63, wid = t >> 6;
  const int wy = wid >> 1, wx = wid & 1;
  const int m = lane & 15, quad = lane >> 4;
  const int srow = t >> 2, scb = (t & 3) * 16;
  const u16* gA = A + (mbase + srow) * 1024 + scb;
  const float* gB = B + (nbase + srow) * 1024 + scb;
  uint4 ra0 = *(const uint4*)(gA), ra1 = *(const uint4*)(gA + 8);
  float4 rb0 = *(const float4*)(gB),     rb1 = *(const float4*)(gB + 4);
  float4 rb2 = *(const float4*)(gB + 8), rb3 = *(const float4*)(gB + 12);

  f32x4 acc[2][2];
#pragma unroll
  for (int i = 0; i < 2; i++)
#pragma unroll
    for (int j = 0; j < 2; j++) acc[i][j] = (f32x4){0.f, 0.f, 0.f, 0.f};

  for (int kb_ = 0; kb_ < 16; ++kb_) {
    __syncthreads();
    *(uint4*)(&sA[srow * 72 + scb])     = ra0;
    *(uint4*)(&sA[srow * 72 + scb + 8]) = ra1;
    *(uint4*)(&sB[srow * 72 + scb])     = pk8(rb0, rb1);
    *(uint4*)(&sB[srow * 72 + scb + 8]) = pk8(rb2, rb3);
    if (kb_ < 15) {
      ra0 = *(const uint4*)(gA + (kb_ + 1) * 64);
      ra1 = *(const uint4*)(gA + (kb_ + 1) * 64 + 8);
      const float* pB = gB + (kb_ + 1) * 64;
      rb0 = *(const float4*)(pB);     rb1 = *(const float4*)(pB + 4);
      rb2 = *(const float4*)(pB + 8); rb3 = *(const float4*)(pB + 12);
    }
    __syncthreads();
    short8 af[2][2], bf[2][2];
#pragma unroll
    for (int mi = 0; mi < 2; mi++)
#pragma unroll
      for (int ks = 0; ks < 2; ks++)
        af[mi][ks] = *(const short8*)(
            &sA[(wy * 32 + mi * 16 + m) * 72 + ks * 32 + quad * 8]);
#pragma unroll
    for (int ni = 0; ni < 2; ni++)
#pragma unroll
      for (int ks = 0; ks < 2; ks++)
        bf[ni][ks] = *(const short8*)(
            &sB[(wx * 32 + ni * 16 + m) * 72 + ks * 32 + quad * 8]);
#pragma unroll
    for (int ks = 0; ks < 2; ks++)
#pragma unroll
      for (int mi = 0; mi < 2; mi++)
#pragma unroll
        for (int ni = 0; ni < 2; ni++)
          acc[mi][ni] = __builtin_amdgcn_mfma_f32_16x16x32_bf16(
              af[mi][ks], bf[ni][ks], acc[mi][ni], 0, 0, 0);
  }

#pragma unroll
  for (int mi = 0; mi < 2; mi++)
#pragma unroll
    for (int ni = 0; ni < 2; ni++) {
      const int col = nbase + wx * 32 + ni * 16 + m;
      const float bcol = bias[col];
#pragma unroll
      for (int r = 0; r < 4; r++) {
        const int row = mbase + wy * 32 + mi * 16 + quad * 4 + r;
        out[row * 1024 + col] =
            b2f(Res[row * 1024 + col]) + fmaxf(acc[mi][ni][r] + bcol, 0.f);
      }
    }
}

// ---------------------------------------------------------------------------
extern "C" void kernel_launch(void* const* d_in, const int* in_sizes, int n_in,
                              void* d_out, int out_size, void* d_ws, size_t ws_size,
                              hipStream_t stream) {
  const float* Q  = (const float*)d_in[0];
  const float* K  = (const float*)d_in[1];
  const float* Wq = (const float*)d_in[2];
  const float* bq = (const float*)d_in[3];
  const float* Wk = (const float*)d_in[4];
  const float* bk = (const float*)d_in[5];
  const float* Wv = (const float*)d_in[6];
  const float* bv = (const float*)d_in[7];
  const float* Wo = (const float*)d_in[8];
  const float* bo = (const float*)d_in[9];
  float* out = (float*)d_out;

  u16* ws = (u16*)d_ws;            // 256 MB ws; flat layout
  u16* qb  = ws;                   // 2M u16
  u16* kb  = qb  + 2097152;        // 2M
  u16* vT  = kb  + 2097152;        // 2M  (v projected TRANSPOSED [1024][2048])
  u16* ob  = vT  + 2097152;        // 2M  (attention out, scrambled)
  u16* po  = ob  + 2097152;        // 8M  (4 splits x 16 h x 2048 q x 64 d)
  float* lp = (float*)(po + 8388608);  // 4x16x2048 fp32
  unsigned* cnt = (unsigned*)(lp + 131072);  // 128 group counters

  hipMemsetAsync(cnt, 0, 512, stream);

  gemm3<<<dim3(512, 3), 256, 0, stream>>>(Q, K, Wq, Wk, Wv, bq, bk, bv,
                                          qb, kb, vT);

  flash<<<dim3(8, 16, 4), 256, 0, stream>>>(qb, kb, vT, po, lp, ob, cnt);

  gemm_out<<<512, 256, 0, stream>>>(ob, Wo, bo, ob, out);
}